// Round 6
// baseline (126.347 us; speedup 1.0000x reference)
//
#include <hip/hip_runtime.h>
#include <hip/hip_bf16.h>
#include <math.h>

#define NN 512
#define DIMX 384
#define HH 8
#define PAIRD 128

#define SCALAR_SCALE 0.144337567297406f   // (3*16)^-0.5
#define POINT_SCALE  0.136082763487954f   // (12*4.5)^-0.5
#define PAIR_SCALE   0.577350269189626f   // 3^-0.5

#define KSL 8
#define KPER 160      // 1280 / KSL
#define PCH 1264      // floats per (i, jc) attn partial chunk

// ---------------- Kernel 1a: unified projection GEMM ----------------
__global__ __launch_bounds__(256) void k_proj_gemm(
    const float* __restrict__ x,
    const float* __restrict__ Wsq, const float* __restrict__ Wsk, const float* __restrict__ Wsv,
    const float* __restrict__ Wpq, const float* __restrict__ Wpk, const float* __restrict__ Wpv,
    float* __restrict__ qs, float* __restrict__ ks, float* __restrict__ vs,
    float* __restrict__ plq, float* __restrict__ plk, float* __restrict__ plv)
{
    const int m0 = blockIdx.x * 64;
    const int t  = blockIdx.y;   // 0..20
    int ldw, c0;
    const float* W;
    float* out;
    if (t < 12) {
        const float* Ws[3] = {Wsq, Wsk, Wsv};
        float* outs[3] = {qs, ks, vs};
        W = Ws[t >> 2]; out = outs[t >> 2]; c0 = (t & 3) * 32; ldw = 128;
    } else {
        const int u = t - 12;
        const float* Wp[3] = {Wpq, Wpk, Wpv};
        float* outp[3] = {plq, plk, plv};
        W = Wp[u / 3]; out = outp[u / 3]; c0 = (u % 3) * 32; ldw = 96;
    }
    const int tid = threadIdx.x;
    __shared__ float xs[32][68];
    __shared__ float Bs[32][36];
    const int tx = tid & 15, ty = tid >> 4;
    float acc[4][2] = {};

    for (int kt = 0; kt < DIMX; kt += 32) {
        #pragma unroll
        for (int it = 0; it < 2; ++it) {
            int l = tid + it * 256;
            int row = l >> 3, kq = l & 7;
            float4 a = *(const float4*)&x[(size_t)(m0 + row) * DIMX + kt + kq * 4];
            xs[kq*4+0][row] = a.x; xs[kq*4+1][row] = a.y;
            xs[kq*4+2][row] = a.z; xs[kq*4+3][row] = a.w;
        }
        {
            int kk = tid >> 3, nq = tid & 7;
            float4 b = *(const float4*)&W[(size_t)(kt + kk) * ldw + c0 + nq * 4];
            *(float4*)&Bs[kk][nq * 4] = b;
        }
        __syncthreads();
        #pragma unroll
        for (int k = 0; k < 32; ++k) {
            float4 a  = *(const float4*)&xs[k][ty * 4];
            float2 bv = *(const float2*)&Bs[k][tx * 2];
            acc[0][0] += a.x * bv.x; acc[0][1] += a.x * bv.y;
            acc[1][0] += a.y * bv.x; acc[1][1] += a.y * bv.y;
            acc[2][0] += a.z * bv.x; acc[2][1] += a.z * bv.y;
            acc[3][0] += a.w * bv.x; acc[3][1] += a.w * bv.y;
        }
        __syncthreads();
    }
    #pragma unroll
    for (int r = 0; r < 4; ++r) {
        float2 v = make_float2(acc[r][0], acc[r][1]);
        *(float2*)&out[(size_t)(m0 + ty * 4 + r) * ldw + c0 + tx * 2] = v;
    }
}

// ---------------- Kernel 1b: frame transform ----------------
__global__ __launch_bounds__(256) void k_frames(
    const float* __restrict__ plq, const float* __restrict__ plk, const float* __restrict__ plv,
    const float* __restrict__ rot, const float* __restrict__ trans,
    float* __restrict__ qp, float* __restrict__ kp, float* __restrict__ vp)
{
    int g = blockIdx.x * 256 + threadIdx.x;
    int m = g >> 14;
    int rem = g & 16383;
    int i = rem >> 5;
    int p = rem & 31;
    const float* pl = (m == 0 ? plq : (m == 1 ? plk : plv));
    float*       o  = (m == 0 ? qp  : (m == 1 ? kp  : vp));
    const float* l = &pl[(size_t)i * 96 + p * 3];
    const float* R = &rot[(size_t)i * 9];
    const float* T = &trans[(size_t)i * 3];
    float l0 = l[0], l1 = l[1], l2 = l[2];
    float* op = o + (size_t)i * 96 + p * 3;
    #pragma unroll
    for (int c = 0; c < 3; ++c)
        op[c] = l0 * R[0 * 3 + c] + l1 * R[1 * 3 + c] + l2 * R[2 * 3 + c] + T[c];
}

// ---------------- Kernel 2: fused attention, 4-way j-split ----------------
// block = (jc, i): residue i, j-chunk of 128. Online softmax over 4 tiles of 32.
// Writes per-chunk partials: accP[8][128] | accS[128] | accV[96] | m[8] | l[8].
__global__ __launch_bounds__(256) void k_attn(
    const float* __restrict__ pair,
    const float* __restrict__ qs, const float* __restrict__ ks,
    const float* __restrict__ qp, const float* __restrict__ kp,
    const float* __restrict__ vs, const float* __restrict__ vp,
    const float* __restrict__ Wpair, const float* __restrict__ bpair,
    const float* __restrict__ pwts,
    float* __restrict__ attnp)
{
    const int jc  = blockIdx.x;      // 0..3
    const int i   = blockIdx.y;      // 0..511
    const int tid = threadIdx.x;

    __shared__ float smem[5768];     // 23.1 KB
    float* pt   = smem;              // [32][132] pair tile
    float* wpt  = smem + 4224;       // [8][128]  W_pair^T
    float* wt   = smem + 5248;       // [8][36]   logits -> weights
    float* cb   = smem + 5536;       // [8] rescale
    float* qs_s = smem + 5544;       // [128]
    float* qp_s = smem + 5672;       // [96]

    // init: W_pair transpose (coalesced global), q vectors
    for (int l = tid; l < 1024; l += 256) {
        float v = Wpair[l];
        wpt[(l & 7) * 128 + (l >> 3)] = v;
    }
    if (tid < 32) ((float4*)qs_s)[tid] = ((const float4*)(qs + (size_t)i * 128))[tid];
    if (tid < 24) ((float4*)qp_s)[tid] = ((const float4*)(qp + (size_t)i * 96))[tid];

    const int g   = tid & 7;         // logits mapping: head / p-slice lane
    const int jjL = tid >> 3;        // logits mapping: j within tile
    const int h2  = tid >> 5;        // softmax/acc mapping: head / j-group
    const int jj2 = tid & 31;        // softmax: j ; acc: float4 channel
    const int jg  = h2, pq = jj2;

    const float bp_h = bpair[g];
    const float pw_h = log1pf(__expf(pwts[g]));

    float m_run = -1e30f, l_run = 0.f;
    float4 accP[8];
    #pragma unroll
    for (int z = 0; z < 8; ++z) accP[z] = make_float4(0, 0, 0, 0);
    float4 accS = make_float4(0, 0, 0, 0);
    float4 accV = make_float4(0, 0, 0, 0);

    const float4* pair4 = (const float4*)(pair + ((size_t)i * NN + jc * 128) * PAIRD);
    const float4* vs4   = (const float4*)vs;
    const float4* vp4   = (const float4*)vp;

    float4 r0 = pair4[tid], r1 = pair4[tid + 256], r2 = pair4[tid + 512], r3 = pair4[tid + 768];

    for (int t = 0; t < 4; ++t) {
        // write prefetched tile (row = l>>5, col4 = l&31)
        *(float4*)&pt[(tid >> 5) * 132 + (tid & 31) * 4]         = r0;
        *(float4*)&pt[((tid + 256) >> 5) * 132 + (tid & 31) * 4] = r1;
        *(float4*)&pt[((tid + 512) >> 5) * 132 + (tid & 31) * 4] = r2;
        *(float4*)&pt[((tid + 768) >> 5) * 132 + (tid & 31) * 4] = r3;
        __syncthreads();                              // A: tile ready

        if (t < 3) {
            const float4* nx = pair4 + (size_t)(t + 1) * 1024;
            r0 = nx[tid]; r1 = nx[tid + 256]; r2 = nx[tid + 512]; r3 = nx[tid + 768];
        }

        // ---- logits: thread (g, jjL); each pair-row element read ONCE ----
        float b[8] = {0,0,0,0,0,0,0,0};
        #pragma unroll
        for (int q = 0; q < 4; ++q) {
            float4 a = *(const float4*)&pt[jjL * 132 + q * 32 + g * 4];
            #pragma unroll
            for (int z = 0; z < 8; ++z) {
                float4 w = *(const float4*)&wpt[z * 128 + q * 32 + g * 4];
                b[z] += a.x * w.x + a.y * w.y + a.z * w.z + a.w * w.w;
            }
        }
        // butterfly reduce over 8-lane p-slice group; lane g keeps head g
        float v0, v1, v2, v3, w0, w1, bias;
        {
            float o0 = __shfl_xor(b[0], 4), o1 = __shfl_xor(b[1], 4);
            float o2 = __shfl_xor(b[2], 4), o3 = __shfl_xor(b[3], 4);
            float o4 = __shfl_xor(b[4], 4), o5 = __shfl_xor(b[5], 4);
            float o6 = __shfl_xor(b[6], 4), o7 = __shfl_xor(b[7], 4);
            bool s2 = (g & 4);
            v0 = s2 ? (b[4] + o4) : (b[0] + o0);
            v1 = s2 ? (b[5] + o5) : (b[1] + o1);
            v2 = s2 ? (b[6] + o6) : (b[2] + o2);
            v3 = s2 ? (b[7] + o7) : (b[3] + o3);
            float p0 = __shfl_xor(v0, 2), p1 = __shfl_xor(v1, 2);
            float p2 = __shfl_xor(v2, 2), p3 = __shfl_xor(v3, 2);
            bool s1 = (g & 2);
            w0 = s1 ? (v2 + p2) : (v0 + p0);
            w1 = s1 ? (v3 + p3) : (v1 + p1);
            float q0 = __shfl_xor(w0, 1), q1 = __shfl_xor(w1, 1);
            bias = (g & 1) ? (w1 + q1) : (w0 + q0);
        }

        const int j = jc * 128 + t * 32 + jjL;
        float sc = 0.f;
        {
            const float4* kr4 = (const float4*)(ks + (size_t)j * 128 + g * 16);
            const float4* qr4 = (const float4*)&qs_s[g * 16];
            #pragma unroll
            for (int q = 0; q < 4; ++q) {
                float4 kq = kr4[q], qq = qr4[q];
                sc += qq.x * kq.x + qq.y * kq.y + qq.z * kq.z + qq.w * kq.w;
            }
        }
        float d2 = 0.f;
        {
            const float4* kp4 = (const float4*)(kp + (size_t)j * 96 + g * 12);
            const float4* qp4 = (const float4*)&qp_s[g * 12];
            #pragma unroll
            for (int q = 0; q < 3; ++q) {
                float4 kq = kp4[q], qq = qp4[q];
                float dx = qq.x - kq.x, dy = qq.y - kq.y, dz = qq.z - kq.z, dw = qq.w - kq.w;
                d2 += dx * dx + dy * dy + dz * dz + dw * dw;
            }
        }
        wt[g * 36 + jjL] = sc * SCALAR_SCALE + (bias + bp_h) * PAIR_SCALE
                         - 0.5f * POINT_SCALE * pw_h * d2;
        __syncthreads();                              // B: raw logits ready

        // ---- online softmax: thread (h2, jj2) holds running state ----
        {
            float lg = wt[h2 * 36 + jj2];
            float tm = lg;
            #pragma unroll
            for (int off = 16; off > 0; off >>= 1) tm = fmaxf(tm, __shfl_xor(tm, off));
            float m_new = fmaxf(m_run, tm);
            float corr  = __expf(m_run - m_new);
            float p     = __expf(lg - m_new);
            float ps    = p;
            #pragma unroll
            for (int off = 16; off > 0; off >>= 1) ps += __shfl_xor(ps, off);
            l_run = l_run * corr + ps;
            m_run = m_new;
            wt[h2 * 36 + jj2] = p;
            if (jj2 == 0) cb[h2] = corr;
        }
        __syncthreads();                              // C: weights ready

        // ---- accumulate: thread (jg, pq) ----
        #pragma unroll
        for (int z = 0; z < 8; ++z) {
            float c = cb[z];
            accP[z].x *= c; accP[z].y *= c; accP[z].z *= c; accP[z].w *= c;
        }
        {
            float c = cb[pq >> 2];
            accS.x *= c; accS.y *= c; accS.z *= c; accS.w *= c;
        }
        if (pq < 24) {
            float c = cb[pq / 3];
            accV.x *= c; accV.y *= c; accV.z *= c; accV.w *= c;
        }
        #pragma unroll
        for (int jo = 0; jo < 4; ++jo) {
            const int jl = jo * 8 + jg;
            const int jglob = jc * 128 + t * 32 + jl;
            float4 pr = *(const float4*)&pt[jl * 132 + pq * 4];
            #pragma unroll
            for (int z = 0; z < 8; ++z) {
                float a = wt[z * 36 + jl];
                accP[z].x += a * pr.x; accP[z].y += a * pr.y;
                accP[z].z += a * pr.z; accP[z].w += a * pr.w;
            }
            {
                float a = wt[(pq >> 2) * 36 + jl];
                float4 v = vs4[(size_t)jglob * 32 + pq];
                accS.x += a * v.x; accS.y += a * v.y; accS.z += a * v.z; accS.w += a * v.w;
            }
            if (pq < 24) {
                float a = wt[(pq / 3) * 36 + jl];
                float4 v = vp4[(size_t)jglob * 24 + pq];
                accV.x += a * v.x; accV.y += a * v.y; accV.z += a * v.z; accV.w += a * v.w;
            }
        }
        __syncthreads();                              // D: tile consumed
    }

    float* attnc = attnp + ((size_t)i * 4 + jc) * PCH;
    if (jj2 == 0) { attnc[1248 + h2] = m_run; attnc[1256 + h2] = l_run; }

    // cross-wave combine: xor-32, then 4 group-pairs via LDS (aliases pt/wpt)
    #pragma unroll
    for (int z = 0; z < 8; ++z) {
        accP[z].x += __shfl_xor(accP[z].x, 32); accP[z].y += __shfl_xor(accP[z].y, 32);
        accP[z].z += __shfl_xor(accP[z].z, 32); accP[z].w += __shfl_xor(accP[z].w, 32);
    }
    accS.x += __shfl_xor(accS.x, 32); accS.y += __shfl_xor(accS.y, 32);
    accS.z += __shfl_xor(accS.z, 32); accS.w += __shfl_xor(accS.w, 32);
    accV.x += __shfl_xor(accV.x, 32); accV.y += __shfl_xor(accV.y, 32);
    accV.z += __shfl_xor(accV.z, 32); accV.w += __shfl_xor(accV.w, 32);

    float4* redP = (float4*)smem;               // [4][8][32] = 16 KB
    float4* redS = (float4*)(smem + 4224);      // [4][32]
    float4* redV = (float4*)(smem + 4736);      // [4][24]
    const int jgp = jg >> 1;
    if ((jg & 1) == 0) {
        #pragma unroll
        for (int z = 0; z < 8; ++z) redP[(jgp * 8 + z) * 32 + pq] = accP[z];
        redS[jgp * 32 + pq] = accS;
        if (pq < 24) redV[jgp * 24 + pq] = accV;
    }
    __syncthreads();                              // E

    {
        const int z = tid >> 5, p4 = tid & 31;
        float4 s = redP[z * 32 + p4];
        #pragma unroll
        for (int gg = 1; gg < 4; ++gg) {
            float4 v = redP[(gg * 8 + z) * 32 + p4];
            s.x += v.x; s.y += v.y; s.z += v.z; s.w += v.w;
        }
        *(float4*)&attnc[z * 128 + p4 * 4] = s;
    }
    if (tid < 32) {
        float4 s = redS[tid];
        #pragma unroll
        for (int gg = 1; gg < 4; ++gg) {
            float4 v = redS[gg * 32 + tid];
            s.x += v.x; s.y += v.y; s.z += v.z; s.w += v.w;
        }
        *(float4*)&attnc[1024 + tid * 4] = s;
    } else if (tid < 56) {
        const int pc = tid - 32;
        float4 s = redV[pc];
        #pragma unroll
        for (int gg = 1; gg < 4; ++gg) {
            float4 v = redV[gg * 24 + pc];
            s.x += v.x; s.y += v.y; s.z += v.z; s.w += v.w;
        }
        *(float4*)&attnc[1152 + pc * 4] = s;
    }
}

// ---------------- Kernel 3: merge chunk partials -> feats ----------------
__global__ __launch_bounds__(256) void k_attn_merge(
    const float* __restrict__ attnp,
    const float* __restrict__ rot, const float* __restrict__ trans,
    float* __restrict__ feats)
{
    const int i = blockIdx.x;
    const int tid = threadIdx.x;
    __shared__ float sm_m[32], sm_l[32], sW[32], sL[8], pts_s[96];

    const float* base = attnp + (size_t)i * 4 * PCH;
    if (tid < 32) {
        int jcx = tid >> 3, h = tid & 7;
        sm_m[jcx * 8 + h] = base[jcx * PCH + 1248 + h];
        sm_l[jcx * 8 + h] = base[jcx * PCH + 1256 + h];
    }
    __syncthreads();
    if (tid < 8) {
        const int h = tid;
        float M = fmaxf(fmaxf(sm_m[h], sm_m[8 + h]), fmaxf(sm_m[16 + h], sm_m[24 + h]));
        float L = 0.f;
        #pragma unroll
        for (int jcx = 0; jcx < 4; ++jcx) {
            float w = __expf(sm_m[jcx * 8 + h] - M);
            L += sm_l[jcx * 8 + h] * w;
            sW[jcx * 8 + h] = w;
        }
        sL[h] = L;
    }
    __syncthreads();

    {   // out_pair
        const int h = tid >> 5, pq = tid & 31;
        float4 s = make_float4(0, 0, 0, 0);
        #pragma unroll
        for (int jcx = 0; jcx < 4; ++jcx) {
            float4 a = *(const float4*)&base[jcx * PCH + h * 128 + pq * 4];
            float w = sW[jcx * 8 + h];
            s.x += a.x * w; s.y += a.y * w; s.z += a.z * w; s.w += a.w * w;
        }
        float inv = 1.f / sL[h];
        s.x *= inv; s.y *= inv; s.z *= inv; s.w *= inv;
        ((float4*)&feats[(size_t)i * 1280 + 256])[tid] = s;
    }
    if (tid < 32) {      // out_s
        const int h = tid >> 2;
        float4 s = make_float4(0, 0, 0, 0);
        #pragma unroll
        for (int jcx = 0; jcx < 4; ++jcx) {
            float4 a = *(const float4*)&base[jcx * PCH + 1024 + tid * 4];
            float w = sW[jcx * 8 + h];
            s.x += a.x * w; s.y += a.y * w; s.z += a.z * w; s.w += a.w * w;
        }
        float inv = 1.f / sL[h];
        s.x *= inv; s.y *= inv; s.z *= inv; s.w *= inv;
        ((float4*)&feats[(size_t)i * 1280])[tid] = s;
    } else if (tid < 56) {   // points
        const int pc = tid - 32;
        const int h = pc / 3;
        float4 s = make_float4(0, 0, 0, 0);
        #pragma unroll
        for (int jcx = 0; jcx < 4; ++jcx) {
            float4 a = *(const float4*)&base[jcx * PCH + 1152 + pc * 4];
            float w = sW[jcx * 8 + h];
            s.x += a.x * w; s.y += a.y * w; s.z += a.z * w; s.w += a.w * w;
        }
        float inv = 1.f / sL[h];
        s.x *= inv; s.y *= inv; s.z *= inv; s.w *= inv;
        ((float4*)pts_s)[pc] = s;
    }
    __syncthreads();

    if (tid < 32) {
        const float* R = &rot[(size_t)i * 9];
        const float* T = &trans[(size_t)i * 3];
        float px = pts_s[tid * 3 + 0] - T[0];
        float py = pts_s[tid * 3 + 1] - T[1];
        float pz = pts_s[tid * 3 + 2] - T[2];
        float n2 = 0.f;
        float* fo = feats + (size_t)i * 1280;
        #pragma unroll
        for (int r = 0; r < 3; ++r) {
            float lr = px * R[r * 3 + 0] + py * R[r * 3 + 1] + pz * R[r * 3 + 2];
            fo[128 + tid * 3 + r] = lr;
            n2 += lr * lr;
        }
        fo[224 + tid] = sqrtf(n2 + 1e-8f);
    }
}

// ---------------- Kernel 5a: final GEMM, split-K, 128x128 tile ----------------
__global__ __launch_bounds__(256) void k_final_gemm(
    const float* __restrict__ feats, const float* __restrict__ Wout,
    float* __restrict__ partial)
{
    const int m0 = blockIdx.x * 128;
    const int n0 = blockIdx.y * 128;
    const int ks = blockIdx.z;
    const int tid = threadIdx.x;
    const int k0 = ks * KPER;
    __shared__ float As[16][132];
    __shared__ float Bs[16][132];
    const int tx = tid & 15, ty = tid >> 4;
    float acc[8][8] = {};

    for (int kt = 0; kt < KPER; kt += 16) {
        #pragma unroll
        for (int it = 0; it < 2; ++it) {
            const int l = tid + it * 256;
            const int row = l >> 2, kq = l & 3;
            float4 a = *(const float4*)&feats[(size_t)(m0 + row) * 1280 + k0 + kt + kq * 4];
            As[kq * 4 + 0][row] = a.x; As[kq * 4 + 1][row] = a.y;
            As[kq * 4 + 2][row] = a.z; As[kq * 4 + 3][row] = a.w;
            const int kk = l >> 5, nq = l & 31;
            float4 b = *(const float4*)&Wout[(size_t)(k0 + kt + kk) * 384 + n0 + nq * 4];
            *(float4*)&Bs[kk][nq * 4] = b;
        }
        __syncthreads();
        #pragma unroll
        for (int k = 0; k < 16; ++k) {
            float4 a0 = *(const float4*)&As[k][ty * 8];
            float4 a1 = *(const float4*)&As[k][ty * 8 + 4];
            float4 b0 = *(const float4*)&Bs[k][tx * 8];
            float4 b1 = *(const float4*)&Bs[k][tx * 8 + 4];
            float am[8] = {a0.x, a0.y, a0.z, a0.w, a1.x, a1.y, a1.z, a1.w};
            float bn[8] = {b0.x, b0.y, b0.z, b0.w, b1.x, b1.y, b1.z, b1.w};
            #pragma unroll
            for (int r = 0; r < 8; ++r)
                #pragma unroll
                for (int c = 0; c < 8; ++c)
                    acc[r][c] += am[r] * bn[c];
        }
        __syncthreads();
    }
    float* po = partial + (size_t)ks * (512 * 384);
    #pragma unroll
    for (int r = 0; r < 8; ++r) {
        *(float4*)&po[(size_t)(m0 + ty * 8 + r) * 384 + n0 + tx * 8]     = *(float4*)&acc[r][0];
        *(float4*)&po[(size_t)(m0 + ty * 8 + r) * 384 + n0 + tx * 8 + 4] = *(float4*)&acc[r][4];
    }
}

// ---------------- Kernel 5b: split-K reduce + bias ----------------
__global__ __launch_bounds__(256) void k_reduce(
    const float* __restrict__ partial, const float* __restrict__ bout,
    float* __restrict__ out)
{
    const int f = blockIdx.x * 256 + threadIdx.x;
    const int e = f * 4;
    const int col = e % 384;
    float4 acc = *(const float4*)&bout[col];
    #pragma unroll
    for (int s = 0; s < KSL; ++s) {
        float4 p = *(const float4*)&partial[(size_t)s * (512 * 384) + e];
        acc.x += p.x; acc.y += p.y; acc.z += p.z; acc.w += p.w;
    }
    *(float4*)&out[e] = acc;
}

extern "C" void kernel_launch(void* const* d_in, const int* in_sizes, int n_in,
                              void* d_out, int out_size, void* d_ws, size_t ws_size,
                              hipStream_t stream) {
    const float* x     = (const float*)d_in[0];
    const float* pair  = (const float*)d_in[1];
    const float* rot   = (const float*)d_in[2];
    const float* trans = (const float*)d_in[3];
    const float* Wsq   = (const float*)d_in[4];
    const float* Wsk   = (const float*)d_in[5];
    const float* Wsv   = (const float*)d_in[6];
    const float* Wpq   = (const float*)d_in[7];
    const float* Wpk   = (const float*)d_in[8];
    const float* Wpv   = (const float*)d_in[9];
    const float* Wpair = (const float*)d_in[10];
    const float* bpair = (const float*)d_in[11];
    const float* pwts  = (const float*)d_in[12];
    const float* Wout  = (const float*)d_in[13];
    const float* bout  = (const float*)d_in[14];

    float* ws      = (float*)d_ws;
    float* qs      = ws;                    // 512*128
    float* ks      = qs + 512 * 128;
    float* vs      = ks + 512 * 128;
    float* qp      = vs + 512 * 128;        // 512*96
    float* kp      = qp + 512 * 96;
    float* vp      = kp + 512 * 96;
    float* feats   = vp + 512 * 96;         // 512*1280
    float* attnp   = feats + 512 * 1280;    // 2048*1264  (aliases partial)
    float* partial = attnp;                 // KSL*512*384 (used after merge)
    float* plq     = attnp + 2048 * PCH;
    float* plk     = plq + 512 * 96;
    float* plv     = plk + 512 * 96;

    k_proj_gemm<<<dim3(8, 21), 256, 0, stream>>>(x, Wsq, Wsk, Wsv, Wpq, Wpk, Wpv,
                                                 qs, ks, vs, plq, plk, plv);
    k_frames<<<192, 256, 0, stream>>>(plq, plk, plv, rot, trans, qp, kp, vp);
    k_attn<<<dim3(4, 512), 256, 0, stream>>>(pair, qs, ks, qp, kp, vs, vp,
                                             Wpair, bpair, pwts, attnp);
    k_attn_merge<<<512, 256, 0, stream>>>(attnp, rot, trans, feats);
    k_final_gemm<<<dim3(4, 3, KSL), 256, 0, stream>>>(feats, Wout, partial);
    k_reduce<<<192, 256, 0, stream>>>(partial, bout, (float*)d_out);
}